// Round 9
// baseline (130.347 us; speedup 1.0000x reference)
//
#include <hip/hip_runtime.h>
#include <hip/hip_bf16.h>

#define BB   16
#define CIN  256
#define COUT 256
#define WD   256
#define HH   64
#define WWS  64
#define NSP  4096      // HH*WWS
#define KW   9

typedef __attribute__((ext_vector_type(8))) short short8;
typedef __attribute__((ext_vector_type(4))) float f32x4;
typedef unsigned short ushort_t;
typedef unsigned int uint_t;

// workspace layout
#define S_BYTES (BB*CIN*4)                       // 16 KB
#define WT_OFF (S_BYTES)
#define WT_BYTES (BB*9*COUT*CIN*2)               // 18.87 MB
#define X_OFF (WT_OFF + WT_BYTES)
#define X_BYTES (BB*NSP*CIN*2)                   // 33.55 MB
#define ZP_OFF (X_OFF + X_BYTES)
#define ZP_BYTES 4096
#define WS_NEEDED ((size_t)(ZP_OFF + ZP_BYTES))

#define WAITVM0 asm volatile("s_waitcnt vmcnt(0)" ::: "memory")
#define WAITVM4 asm volatile("s_waitcnt vmcnt(4)" ::: "memory")

__device__ inline ushort_t f2bf(float f) {
    __hip_bfloat16 h = __float2bfloat16(f);
    return __builtin_bit_cast(ushort_t, h);
}

__device__ inline void gload_lds16(const ushort_t* g, ushort_t* l) {
    __builtin_amdgcn_global_load_lds(
        (const __attribute__((address_space(1))) void*)g,
        (__attribute__((address_space(3))) void*)l, 16, 0, 0);
}

// ---------------------------------------------------------------------------
// Kernel 1: style modulation
// ---------------------------------------------------------------------------
__global__ __launch_bounds__(256)
void style_kernel(const float* __restrict__ w,
                  const float* __restrict__ style_w,
                  const float* __restrict__ style_b,
                  float* __restrict__ s) {
    const int b  = blockIdx.x;
    const int ci = threadIdx.x;
    __shared__ float wsh[WD];
    wsh[ci] = w[b * WD + ci];
    __syncthreads();
    const float* row = style_w + ci * WD;
    float acc = style_b[ci];
    #pragma unroll 4
    for (int k = 0; k < WD; ++k) acc += wsh[k] * row[k];
    s[b * CIN + ci] = acc;
}

// ---------------------------------------------------------------------------
// Kernel 2: demodulated weights -> bf16, layout [b][tap][co][ci]
//           (block (0,0) also zero-fills the zp page used by conv)
// ---------------------------------------------------------------------------
__global__ __launch_bounds__(256)
void wt_kernel(const float* __restrict__ cw, const float* __restrict__ s,
               const float* __restrict__ scale_p, ushort_t* __restrict__ wt,
               float* __restrict__ zp) {
    const int co = blockIdx.x, b = blockIdx.y, ci = threadIdx.x;
    if (co == 0 && b == 0)
        ((float4*)zp)[ci] = make_float4(0.f, 0.f, 0.f, 0.f);
    const float sv = s[b * CIN + ci] * scale_p[0];
    const float* cp = cw + ((size_t)co * CIN + ci) * KW;
    float v[9];
    float ss = 0.f;
    #pragma unroll
    for (int t = 0; t < 9; ++t) { v[t] = cp[t] * sv; ss += v[t] * v[t]; }
    #pragma unroll
    for (int off = 32; off > 0; off >>= 1) ss += __shfl_down(ss, off);
    __shared__ float red[4];
    if ((ci & 63) == 0) red[ci >> 6] = ss;
    __syncthreads();
    const float dm = rsqrtf(red[0] + red[1] + red[2] + red[3] + 1e-8f);
    #pragma unroll
    for (int t = 0; t < 9; ++t)
        wt[((size_t)(b * 9 + t) * COUT + co) * CIN + ci] = f2bf(v[t] * dm);
}

// ---------------------------------------------------------------------------
// Kernel 3: x NCHW fp32 -> NHWC bf16  (xo[b][sp][ci]); uint4 stores
// ---------------------------------------------------------------------------
__global__ __launch_bounds__(256)
void xpose_kernel(const float* __restrict__ x, ushort_t* __restrict__ xo) {
    const int spt = blockIdx.x;
    const int cit = blockIdx.y;
    const int b   = blockIdx.z;
    const int t   = threadIdx.x;
    __shared__ ushort_t tile[64 * 72];
    const int sp0 = spt * 64, ci0 = cit * 64;
    {
        const int spq = t & 15, cil = t >> 4;
        #pragma unroll
        for (int i = 0; i < 4; ++i) {
            const int ci = cil + i * 16;
            const float4 v = *(const float4*)(x + ((size_t)(b * CIN + ci0 + ci)) * NSP + sp0 + spq * 4);
            tile[(spq * 4 + 0) * 72 + ci] = f2bf(v.x);
            tile[(spq * 4 + 1) * 72 + ci] = f2bf(v.y);
            tile[(spq * 4 + 2) * 72 + ci] = f2bf(v.z);
            tile[(spq * 4 + 3) * 72 + ci] = f2bf(v.w);
        }
    }
    __syncthreads();
    {
        const int g8 = t & 7, sp = t >> 3;     // sp 0..31
        #pragma unroll
        for (int i = 0; i < 2; ++i) {
            const int spp = sp + i * 32;
            uint4 v = *(const uint4*)&tile[spp * 72 + g8 * 8];
            *(uint4*)(xo + ((size_t)(b * NSP + sp0 + spp)) * CIN + ci0 + g8 * 8) = v;
        }
    }
}

// ---------------------------------------------------------------------------
// Kernel 4: implicit-GEMM conv, x-resident + A-direct-to-register.
//   256 blocks (16 b x 16 ntile), 512 threads = 8 waves (4M x 2N).
//   Block tile 256 co x 256 sp; wave tile 64co x 128sp -> acc[4][8].
//   x: LDS-RESIDENT per ci-half: [6 rows][66 cols][128 ci] = 101 KB, staged
//      once per half via 96 global_load_lds calls (12/wave). Halo cols 0/65
//      zeroed once. XOR-pos swizzle pos=(chunk*4+lg)^((l15+kx)&15) on both
//      DMA source and ds_read -> uniform 8 lanes/bank (b128 minimum).
//   A: NO LDS. af frags loaded global->reg (4 x dwordx4/tap from L2-resident
//      wt), double-set, issued AFTER the MFMA burst (2-tap pipeline),
//      synced by per-wave counted vmcnt(4). Steady state: 0 barriers, 0 DMA.
//   Per tap per wave: 8 ds_read_b128 (bf) + 32 MFMA + 4 global loads.
// ---------------------------------------------------------------------------
__global__ __launch_bounds__(512, 2)
void conv_mfma_kernel(const ushort_t* __restrict__ wt,   // [b][9][256][256]
                      const ushort_t* __restrict__ xo,   // [b][4096][256]
                      const ushort_t* __restrict__ zp,   // zero page
                      float* __restrict__ out) {
    const int wg    = blockIdx.x;              // 0..255
    const int b     = (wg & 7) | (((wg >> 3) & 1) << 3);  // batch per XCD
    const int ntile = wg >> 4;                 // 0..15
    const int y0    = ntile * 4;

    const int tid  = threadIdx.x;
    const int lane = tid & 63;
    const int w    = tid >> 6;                 // wave 0..7
    const int wm   = w >> 1;                   // co quarter
    const int wn   = w & 1;                    // spatial half
    const int wn2  = wn * 2;
    const int l15  = lane & 15;
    const int lg   = lane >> 4;                // ci quad within 32-chunk

    // x resident: [6 rows][66 cols][16 quad-slots of 8 ushorts]
    __shared__ __align__(16) ushort_t lds_x[6 * 66 * 128];   // 101376 B

    // ---- A direct-load base (per lane): wt[((b*9+tap)*256+co)*256+ci] ----
    const ushort_t* pa = wt + (size_t)b * (9 * COUT * CIN)
                       + (uint_t)(wm * 64 + l15) * CIN + (uint_t)(lg * 8);

    const ushort_t* xob = xo + (size_t)b * (NSP * CIN);

    f32x4 acc[4][8];
    #pragma unroll
    for (int mi = 0; mi < 4; ++mi)
        #pragma unroll
        for (int ni = 0; ni < 8; ++ni) acc[mi][ni] = (f32x4){0.f, 0.f, 0.f, 0.f};

    short8 af[2][4];

    // ---- zero halo cols (0 and 65), once (tid<192, 16B each) ----
    if (tid < 192) {
        const int r = tid / 32, rem = tid % 32;
        const int c = (rem & 1) * 65, q2 = rem >> 1;
        *(uint4*)&lds_x[r * 8448 + c * 128 + q2 * 8] = make_uint4(0, 0, 0, 0);
    }

    // ---- x staging: 12 calls/wave cover 96 regions (6 rows x 16 colquads) --
    #define STAGE_X(hh)                                                        \
    {   _Pragma("unroll")                                                      \
        for (int i_ = 0; i_ < 12; ++i_) {                                      \
            const int id_ = w + 8 * i_;                                        \
            const int r_  = id_ >> 4;          /* 0..5 */                      \
            const int cg_ = id_ & 15;          /* colquad */                   \
            const int y_  = y0 - 1 + r_;                                       \
            const int colIdx_ = 1 + cg_ * 4 + (lane >> 4);                     \
            const int sq_ = (lane & 15) ^ (colIdx_ & 15);                      \
            const ushort_t* src_ = (y_ >= 0 && y_ < HH)                        \
                ? (xob + (uint_t)(y_ * WWS + cg_ * 4 + (lane >> 4)) * CIN      \
                       + (hh) * 128 + sq_ * 8)                                 \
                : (zp + (lane & 15) * 8);                                      \
            gload_lds16(src_, lds_x + r_ * 8448 + (1 + cg_ * 4) * 128          \
                              + lane * 8);                                     \
        }                                                                      \
    }

    STAGE_X(0);
    // issue af(T=0) -> set0, af(T=1) -> set1 (chunkG=0, taps 0,1)
    #pragma unroll
    for (int mi = 0; mi < 4; ++mi)
        af[0][mi] = *(const short8*)(pa + mi * 4096);
    #pragma unroll
    for (int mi = 0; mi < 4; ++mi)
        af[1][mi] = *(const short8*)(pa + 65536 + mi * 4096);

    WAITVM0;                                    // x (and af) landed
    asm volatile("s_waitcnt lgkmcnt(0)" ::: "memory");   // halo writes done
    __builtin_amdgcn_sched_barrier(0);
    __builtin_amdgcn_s_barrier();               // all waves' x visible

    // ---- one tap: bf reads -> MFMA -> issue af(T+2) ----
    #define TAP(t, CHPAR, cgv, xcb)                                            \
    {                                                                          \
        WAITVM4;                      /* af(T) landed; af(T+1) in flight */    \
        __builtin_amdgcn_sched_barrier(0);                                     \
        const int ky_ = (t) / 3, kx_ = (t) % 3;                                \
        const int P_  = ((CHPAR) + (t)) & 1;                                   \
        const ushort_t* bq_ = lds_x + (wn2 + ky_) * 8448 + xcb[kx_];           \
        short8 bf_[8];                                                         \
        _Pragma("unroll")                                                      \
        for (int ni_ = 0; ni_ < 8; ++ni_)                                      \
            bf_[ni_] = *(const short8*)(bq_ + (ni_ >> 2) * 8448                \
                                        + (ni_ & 3) * 2048);                   \
        __builtin_amdgcn_s_setprio(1);                                         \
        _Pragma("unroll")                                                      \
        for (int mi_ = 0; mi_ < 4; ++mi_)                                      \
            _Pragma("unroll")                                                  \
            for (int ni_ = 0; ni_ < 8; ++ni_)                                  \
                acc[mi_][ni_] = __builtin_amdgcn_mfma_f32_16x16x32_bf16(       \
                    bf_[ni_], af[P_][mi_], acc[mi_][ni_], 0, 0, 0);            \
        __builtin_amdgcn_s_setprio(0);                                         \
        __builtin_amdgcn_sched_barrier(0);                                     \
        {   /* issue af(T+2) into set P (just consumed) */                     \
            const int t2_  = ((t) + 2) % 9;                                    \
            const int cg2_ = ((cgv) + (((t) + 2) / 9)) & 7;                    \
            const ushort_t* ap_ = pa + t2_ * 65536 + cg2_ * 32;                \
            _Pragma("unroll")                                                  \
            for (int mi_ = 0; mi_ < 4; ++mi_)                                  \
                af[P_][mi_] = *(const short8*)(ap_ + mi_ * 4096);              \
        }                                                                      \
        __builtin_amdgcn_sched_barrier(0);                                     \
    }

    #define CHUNK9(CHPAR, cgv, clv)                                            \
    {   int xcb[3];                                                            \
        _Pragma("unroll")                                                      \
        for (int kx_ = 0; kx_ < 3; ++kx_) {                                    \
            const int pos_ = ((clv) * 4 + lg) ^ ((l15 + kx_) & 15);            \
            xcb[kx_] = (l15 + kx_) * 128 + pos_ * 8;                           \
        }                                                                      \
        TAP(0, CHPAR, cgv, xcb) TAP(1, CHPAR, cgv, xcb)                        \
        TAP(2, CHPAR, cgv, xcb) TAP(3, CHPAR, cgv, xcb)                        \
        TAP(4, CHPAR, cgv, xcb) TAP(5, CHPAR, cgv, xcb)                        \
        TAP(6, CHPAR, cgv, xcb) TAP(7, CHPAR, cgv, xcb)                        \
        TAP(8, CHPAR, cgv, xcb)                                                \
    }

    #pragma unroll 1
    for (int h = 0; h < 2; ++h) {
        if (h) {
            // restage x for ci-half 1 (af pipeline keeps running in regs)
            asm volatile("s_waitcnt lgkmcnt(0)" ::: "memory");
            __builtin_amdgcn_sched_barrier(0);
            __builtin_amdgcn_s_barrier();      // all waves done reading half 0
            STAGE_X(1);
            WAITVM0;                           // own x calls (and af) landed
            __builtin_amdgcn_sched_barrier(0);
            __builtin_amdgcn_s_barrier();      // all waves' x visible
        }
        #pragma unroll 1
        for (int c2 = 0; c2 < 2; ++c2) {
            const int cl0 = c2 * 2;
            const int cg0 = h * 4 + cl0;
            CHUNK9(0, cg0, cl0)
            const int cl1 = c2 * 2 + 1;
            const int cg1 = h * 4 + cl1;
            CHUNK9(1, cg1, cl1)
        }
    }
    #undef TAP
    #undef CHUNK9
    #undef STAGE_X

    // drain outstanding dummy af loads before epilogue
    asm volatile("s_waitcnt vmcnt(0) lgkmcnt(0)" ::: "memory");
    __builtin_amdgcn_sched_barrier(0);

    // ---- epilogue: D col = co = l15, rows = sp -> f32x4 stores ----
    #pragma unroll
    for (int mi = 0; mi < 4; ++mi) {
        const int co = wm * 64 + mi * 16 + l15;
        float* ob = out + ((size_t)(b * COUT + co)) * NSP
                  + ntile * 256 + wn * 128 + lg * 4;
        #pragma unroll
        for (int ni = 0; ni < 8; ++ni)
            *(f32x4*)(ob + (ni >> 2) * 64 + (ni & 3) * 16) = acc[mi][ni];
    }
}

// ---------------------------------------------------------------------------
// Fallback fp32 direct conv if workspace is too small.
// ---------------------------------------------------------------------------
__global__ __launch_bounds__(256)
void modconv_kernel(const float* __restrict__ x,
                    const float* __restrict__ cw,
                    const float* __restrict__ s,
                    const float* __restrict__ scale_p,
                    float* __restrict__ out) {
    const int tile = blockIdx.x;
    const int co   = blockIdx.y;
    const int b    = blockIdx.z;
    const int tid  = threadIdx.x;
    const float scale = scale_p[0];

    __shared__ float s_wt[CIN * KW];
    __shared__ float s_x[18 * 66];
    __shared__ float red[4];

    const float* cwb = cw + (size_t)co * CIN * KW;
    const float* sb  = s + b * CIN;
    float sumsq = 0.f;
    for (int i = tid; i < CIN * KW; i += 256) {
        float v = cwb[i] * scale * sb[i / KW];
        s_wt[i] = v;
        sumsq += v * v;
    }
    #pragma unroll
    for (int off = 32; off > 0; off >>= 1) sumsq += __shfl_down(sumsq, off);
    if ((tid & 63) == 0) red[tid >> 6] = sumsq;
    __syncthreads();
    const float demod = rsqrtf(red[0] + red[1] + red[2] + red[3] + 1e-8f);
    for (int i = tid; i < CIN * KW; i += 256) s_wt[i] *= demod;

    const int tx = tid & 63;
    const int tr = tid >> 6;
    const int y0 = tile * 16;
    float acc[4] = {0.f, 0.f, 0.f, 0.f};

    for (int ci = 0; ci < CIN; ++ci) {
        __syncthreads();
        const float* xb = x + ((size_t)(b * CIN + ci)) * (HH * WWS);
        for (int idx = tid; idx < 18 * 66; idx += 256) {
            const int r = idx / 66, c = idx % 66;
            const int yg = y0 - 1 + r, xg = c - 1;
            float v = 0.f;
            if (yg >= 0 && yg < HH && xg >= 0 && xg < WWS) v = xb[yg * WWS + xg];
            s_x[idx] = v;
        }
        __syncthreads();
        const float* wr = s_wt + ci * KW;
        const float w0 = wr[0], w1 = wr[1], w2 = wr[2];
        const float w3 = wr[3], w4 = wr[4], w5 = wr[5];
        const float w6 = wr[6], w7 = wr[7], w8 = wr[8];
        const int rbase = tr * 4;
        float xv[6][3];
        #pragma unroll
        for (int j = 0; j < 6; ++j)
            #pragma unroll
            for (int k = 0; k < 3; ++k) xv[j][k] = s_x[(rbase + j) * 66 + tx + k];
        #pragma unroll
        for (int i = 0; i < 4; ++i)
            acc[i] += w0 * xv[i][0] + w1 * xv[i][1] + w2 * xv[i][2]
                    + w3 * xv[i+1][0] + w4 * xv[i+1][1] + w5 * xv[i+1][2]
                    + w6 * xv[i+2][0] + w7 * xv[i+2][1] + w8 * xv[i+2][2];
    }
    float* ob = out + (((size_t)(b * COUT + co)) * HH + y0) * WWS + tx;
    #pragma unroll
    for (int i = 0; i < 4; ++i) ob[(tr * 4 + i) * WWS] = acc[i];
}

// ---------------------------------------------------------------------------
extern "C" void kernel_launch(void* const* d_in, const int* in_sizes, int n_in,
                              void* d_out, int out_size, void* d_ws, size_t ws_size,
                              hipStream_t stream) {
    const float* x       = (const float*)d_in[0];
    const float* w       = (const float*)d_in[1];
    const float* cw      = (const float*)d_in[2];
    const float* style_w = (const float*)d_in[3];
    const float* style_b = (const float*)d_in[4];
    const float* scale_p = (const float*)d_in[5];
    float*       out     = (float*)d_out;

    float*    s    = (float*)d_ws;
    ushort_t* wswt = (ushort_t*)((char*)d_ws + WT_OFF);
    ushort_t* wsx  = (ushort_t*)((char*)d_ws + X_OFF);
    float*    zp   = (float*)((char*)d_ws + ZP_OFF);

    style_kernel<<<dim3(BB), 256, 0, stream>>>(w, style_w, style_b, s);

    if (ws_size >= WS_NEEDED) {
        wt_kernel<<<dim3(COUT, BB), 256, 0, stream>>>(cw, s, scale_p, wswt, zp);
        xpose_kernel<<<dim3(64, 4, BB), 256, 0, stream>>>(x, wsx);
        conv_mfma_kernel<<<dim3(256), 512, 0, stream>>>(wswt, wsx,
                                                        (const ushort_t*)zp, out);
    } else {
        modconv_kernel<<<dim3(4, COUT, BB), 256, 0, stream>>>(x, cw, s, scale_p, out);
    }
}